// Round 3
// baseline (313.553 us; speedup 1.0000x reference)
//
#include <hip/hip_runtime.h>

// SpecAugment: B=64, C=2, F=128, T=2048, fp32.
// out[b,c,f,t] = apply[b] ? (keep[b,f,t] ? spec : 0) + noise*0.01 : spec
// Memory-bound. Round 1 was latency-limited (2.68 TB/s, 1 load-pair/thread).
// This round: 4 float4s per thread (4x outstanding loads) + non-temporal
// output stores (don't evict spec/noise from the 256 MiB L3).
// Round 2 fix: __builtin_nontemporal_store needs a Clang ext_vector_type,
// not HIP's float4 class.

#define BB 64
#define CC 2
#define FF 128
#define TT 2048
#define VPT 4          // vec4s per thread
#define BLOCK 256

typedef float vfloat4 __attribute__((ext_vector_type(4)));

__global__ __launch_bounds__(BLOCK) void specaug_kernel(
    const float* __restrict__ spec,
    const float* __restrict__ apply_u,
    const float* __restrict__ f_width_u,
    const float* __restrict__ f_start_u,
    const float* __restrict__ t_width_u,
    const float* __restrict__ t_start_u,
    const float* __restrict__ noise,
    float* __restrict__ out)
{
    // Block covers BLOCK*VPT = 1024 consecutive vec4s (= 2 (b,c,f) rows).
    // Lanes stay contiguous within each of the VPT strided loads -> coalesced.
    const int base = blockIdx.x * (BLOCK * VPT) + threadIdx.x;
    // 131072 vec4s per batch; 1024 divides 131072 -> b is block-uniform.
    const int b = base >> 17;

    vfloat4 s[VPT];
    #pragma unroll
    for (int j = 0; j < VPT; ++j)
        s[j] = ((const vfloat4*)spec)[base + j * BLOCK];

    if (apply_u[b] <= 0.5f) {
        // Issue all noise loads before any mask math so they overlap.
        vfloat4 n[VPT];
        #pragma unroll
        for (int j = 0; j < VPT; ++j)
            n[j] = ((const vfloat4*)noise)[base + j * BLOCK];

        // Frequency masks (range F - w >= 109 > 0, no clamp needed).
        int fs0[2], fw[2];
        #pragma unroll
        for (int k = 0; k < 2; ++k) {
            const int   w   = (int)floorf(f_width_u[b * 2 + k] * 20.0f);
            const float rng = (float)(FF - w);
            fs0[k] = (int)floorf(f_start_u[b * 2 + k] * rng);
            fw[k]  = w;
        }
        // Time masks (range clamped to >= 1).
        int ts0[2], tw[2];
        #pragma unroll
        for (int k = 0; k < 2; ++k) {
            const int   w   = (int)floorf(t_width_u[b * 2 + k] * 40.0f);
            const float rng = fmaxf((float)(TT - w), 1.0f);
            ts0[k] = (int)floorf(t_start_u[b * 2 + k] * rng);
            tw[k]  = w;
        }

        #pragma unroll
        for (int j = 0; j < VPT; ++j) {
            const int vec = base + j * BLOCK;
            const int tv  = vec & (TT / 4 - 1);
            const int row = vec >> 9;
            const int f   = row & (FF - 1);
            const int t0  = tv << 2;

            bool fmask = false;
            #pragma unroll
            for (int k = 0; k < 2; ++k)
                fmask |= (f >= fs0[k]) & (f < fs0[k] + fw[k]);

            vfloat4 o;
            #pragma unroll
            for (int e = 0; e < 4; ++e) {
                const int t = t0 + e;
                bool tmask = false;
                #pragma unroll
                for (int k = 0; k < 2; ++k)
                    tmask |= (t >= ts0[k]) & (t < ts0[k] + tw[k]);
                const bool keep = (!fmask) & (!tmask);
                o[e] = (keep ? s[j][e] : 0.0f) + n[j][e] * 0.01f;
            }
            __builtin_nontemporal_store(o, (vfloat4*)out + vec);
        }
    } else {
        #pragma unroll
        for (int j = 0; j < VPT; ++j)
            __builtin_nontemporal_store(s[j], (vfloat4*)out + base + j * BLOCK);
    }
}

extern "C" void kernel_launch(void* const* d_in, const int* in_sizes, int n_in,
                              void* d_out, int out_size, void* d_ws, size_t ws_size,
                              hipStream_t stream) {
    const float* spec      = (const float*)d_in[0];
    const float* apply_u   = (const float*)d_in[1];
    const float* f_width_u = (const float*)d_in[2];
    const float* f_start_u = (const float*)d_in[3];
    const float* t_width_u = (const float*)d_in[4];
    const float* t_start_u = (const float*)d_in[5];
    const float* noise     = (const float*)d_in[6];
    float* out             = (float*)d_out;

    const int total_vecs = BB * CC * FF * (TT / 4);        // 8,388,608
    const int grid = total_vecs / (BLOCK * VPT);           // 8192

    specaug_kernel<<<grid, BLOCK, 0, stream>>>(
        spec, apply_u, f_width_u, f_start_u, t_width_u, t_start_u, noise, out);
}

// Round 4
// 307.090 us; speedup vs baseline: 1.0210x; 1.0210x over previous
//
#include <hip/hip_runtime.h>

// SpecAugment: B=64, C=2, F=128, T=2048, fp32.
// out[b,c,f,t] = apply[b] ? (keep[b,f,t] ? spec : 0) + noise*0.01 : spec
// R1: 91 us @ 2.68 TB/s (VPT=1, plain stores) — latency-bound.
// R3: 109 us @ 2.25 TB/s (VPT=4 + nontemporal stores) — REGRESSION.
//     Traffic identical -> nt stores suspected (no L2 write-coalescing).
// R4: VPT=4 ILP kept, plain stores restored, and b/apply/mask params made
//     provably block-uniform (computed from blockIdx only) -> s_load + scalar
//     branch instead of per-lane vmem load feeding the branch.

#define BB 64
#define CC 2
#define FF 128
#define TT 2048
#define VPT 4          // vec4s per thread
#define BLOCK 256

typedef float vfloat4 __attribute__((ext_vector_type(4)));

__global__ __launch_bounds__(BLOCK) void specaug_kernel(
    const float* __restrict__ spec,
    const float* __restrict__ apply_u,
    const float* __restrict__ f_width_u,
    const float* __restrict__ f_start_u,
    const float* __restrict__ t_width_u,
    const float* __restrict__ t_start_u,
    const float* __restrict__ noise,
    float* __restrict__ out)
{
    // Block covers BLOCK*VPT = 1024 consecutive vec4s (= 2 (b,c,f) rows).
    // 131072 vec4s per batch; 1024 divides 131072 -> b depends only on
    // blockIdx -> compiler proves uniformity -> scalar loads for params.
    const int blockBase = blockIdx.x * (BLOCK * VPT);
    const int b    = blockBase >> 17;
    const int base = blockBase + threadIdx.x;

    vfloat4 s[VPT];
    #pragma unroll
    for (int j = 0; j < VPT; ++j)
        s[j] = ((const vfloat4*)spec)[base + j * BLOCK];

    if (apply_u[b] <= 0.5f) {
        // Issue all noise loads before any mask math so they overlap.
        vfloat4 n[VPT];
        #pragma unroll
        for (int j = 0; j < VPT; ++j)
            n[j] = ((const vfloat4*)noise)[base + j * BLOCK];

        // Frequency masks (range F - w >= 109 > 0, no clamp needed).
        int fs0[2], fw[2];
        #pragma unroll
        for (int k = 0; k < 2; ++k) {
            const int   w   = (int)floorf(f_width_u[b * 2 + k] * 20.0f);
            const float rng = (float)(FF - w);
            fs0[k] = (int)floorf(f_start_u[b * 2 + k] * rng);
            fw[k]  = w;
        }
        // Time masks (range clamped to >= 1).
        int ts0[2], tw[2];
        #pragma unroll
        for (int k = 0; k < 2; ++k) {
            const int   w   = (int)floorf(t_width_u[b * 2 + k] * 40.0f);
            const float rng = fmaxf((float)(TT - w), 1.0f);
            ts0[k] = (int)floorf(t_start_u[b * 2 + k] * rng);
            tw[k]  = w;
        }

        #pragma unroll
        for (int j = 0; j < VPT; ++j) {
            const int vec = base + j * BLOCK;
            const int tv  = vec & (TT / 4 - 1);
            const int row = vec >> 9;
            const int f   = row & (FF - 1);
            const int t0  = tv << 2;

            bool fmask = false;
            #pragma unroll
            for (int k = 0; k < 2; ++k)
                fmask |= (f >= fs0[k]) & (f < fs0[k] + fw[k]);

            vfloat4 o;
            #pragma unroll
            for (int e = 0; e < 4; ++e) {
                const int t = t0 + e;
                bool tmask = false;
                #pragma unroll
                for (int k = 0; k < 2; ++k)
                    tmask |= (t >= ts0[k]) & (t < ts0[k] + tw[k]);
                const bool keep = (!fmask) & (!tmask);
                o[e] = (keep ? s[j][e] : 0.0f) + n[j][e] * 0.01f;
            }
            ((vfloat4*)out)[vec] = o;
        }
    } else {
        #pragma unroll
        for (int j = 0; j < VPT; ++j)
            ((vfloat4*)out)[base + j * BLOCK] = s[j];
    }
}

extern "C" void kernel_launch(void* const* d_in, const int* in_sizes, int n_in,
                              void* d_out, int out_size, void* d_ws, size_t ws_size,
                              hipStream_t stream) {
    const float* spec      = (const float*)d_in[0];
    const float* apply_u   = (const float*)d_in[1];
    const float* f_width_u = (const float*)d_in[2];
    const float* f_start_u = (const float*)d_in[3];
    const float* t_width_u = (const float*)d_in[4];
    const float* t_start_u = (const float*)d_in[5];
    const float* noise     = (const float*)d_in[6];
    float* out             = (float*)d_out;

    const int total_vecs = BB * CC * FF * (TT / 4);        // 8,388,608
    const int grid = total_vecs / (BLOCK * VPT);           // 8192

    specaug_kernel<<<grid, BLOCK, 0, stream>>>(
        spec, apply_u, f_width_u, f_start_u, t_width_u, t_start_u, noise, out);
}